// Round 1
// baseline (803.414 us; speedup 1.0000x reference)
//
#include <hip/hip_runtime.h>

typedef unsigned short ushort_t;
typedef __attribute__((ext_vector_type(8))) short   short8_t;
typedef __attribute__((ext_vector_type(4))) float   float4_t;
typedef __attribute__((ext_vector_type(4))) unsigned short ushort4_t;

__device__ __forceinline__ ushort_t f2b(float f) {
    unsigned int u = __float_as_uint(f);
    u += 0x7FFFu + ((u >> 16) & 1u);      // round-to-nearest-even
    return (ushort_t)(u >> 16);
}
__device__ __forceinline__ float b2f(ushort_t s) {
    return __uint_as_float(((unsigned int)s) << 16);
}
__device__ __forceinline__ float frcp(float x) { return __builtin_amdgcn_rcpf(x); }
__device__ __forceinline__ float sigf(float x) { return frcp(1.f + __expf(-x)); }
__device__ __forceinline__ float tanhf_fast(float x) {
    // tanh(x) = 1 - 2/(exp(2x)+1); exp->inf => 1, exp->0 => -1 (graceful)
    return 1.f - 2.f * frcp(__expf(2.f * x) + 1.f);
}

// ---------------- weight convert: fp32 -> bf16 into ws ----------------
// ws layout (ushort elements): [0,196608): rec W [m][col 256][k 256]
//                              [196608, 344064): in W [m][col 256][k 192]
__global__ void cvt_w(const float* __restrict__ ffr, const float* __restrict__ gr,
                      const float* __restrict__ tr,  const float* __restrict__ ffi,
                      const float* __restrict__ gi,  const float* __restrict__ ti,
                      ushort_t* __restrict__ o)
{
    int i = blockIdx.x * 256 + threadIdx.x;   // exactly [0, 344064)
    float v;
    if (i < 196608) {
        int j = i & 65535;
        v = (i < 65536) ? ffr[j] : (i < 131072) ? gr[j] : tr[j];
    } else {
        int j = i - 196608;
        int jj = (j < 49152) ? j : (j < 98304) ? j - 49152 : j - 98304;
        v = (j < 49152) ? ffi[jj] : (j < 98304) ? gi[jj] : ti[jj];
    }
    o[i] = f2b(v);
}

// ---------------- fused LTC kernel ----------------
// grid 256 blocks x 512 thr (8 waves). Block owns batch rows [16*blk, 16*blk+16).
// wave wv owns hidden cols [32*wv, 32*wv+32) of all 3 matrices (2 N-tiles of 16).
// LDS (static, 140800 B):
//   Al: [4 t][16 row][200]   bf16 x-seq chunk (192 used + pad)
//   Pl: [4 t][8 wv][3 m][2 n][256] bf16 projections in MFMA C-lane order
//   Hb: [2 buf][16 row][264] bf16 h (A-fragment source), padded vs bank conflicts
__global__ __launch_bounds__(512, 2) void ltc_fused(
    const float* __restrict__ x,
    const ushort_t* __restrict__ wbf,
    const float* __restrict__ ff_in_b, const float* __restrict__ ff_bias,
    const float* __restrict__ g_in_b,  const float* __restrict__ g_bias,
    const float* __restrict__ t_in_b,  const float* __restrict__ t_bias,
    const float* __restrict__ head_w,  const float* __restrict__ head_b,
    float* __restrict__ out)
{
    __shared__ __align__(16) ushort_t smem[70400];
    ushort_t* Al = smem;                 // 12800 el
    ushort_t* Pl = smem + 12800;         // 49152 el
    ushort_t* Hb = smem + 61952;         // 8448 el

    const int tid   = threadIdx.x;
    const int lane  = tid & 63;
    const int wv    = tid >> 6;
    const int l16   = lane & 15;
    const int l4    = lane >> 4;
    const int bbase = blockIdx.x << 4;

    const ushort_t* wrec = wbf;
    const ushort_t* win  = wbf + 196608;

    // persistent recurrent-weight B-fragments: B[k][n] = W[col][k]
    short8_t wr[3][2][8];
#pragma unroll
    for (int m = 0; m < 3; ++m)
#pragma unroll
        for (int n = 0; n < 2; ++n) {
            const int col = 32*wv + 16*n + l16;
            const ushort_t* src = wrec + (m << 16) + (col << 8) + l4*8;
#pragma unroll
            for (int k = 0; k < 8; ++k)
                wr[m][n][k] = *(const short8_t*)(src + k*32);
        }

    const float* inb[3] = {ff_in_b, g_in_b, t_in_b};
    const float* bbp[3] = {ff_bias, g_bias, t_bias};
    float bias_mn[3][2];
#pragma unroll
    for (int m = 0; m < 3; ++m)
#pragma unroll
        for (int n = 0; n < 2; ++n) {
            const int col = 32*wv + 16*n + l16;
            bias_mn[m][n] = inb[m][col] + bbp[m][col];
        }

    float hp[2][4];
#pragma unroll
    for (int n = 0; n < 2; ++n)
#pragma unroll
        for (int r = 0; r < 4; ++r) hp[n][r] = 0.f;

    for (int i = tid; i < 4224; i += 512) Hb[i] = 0;   // h0 = 0 (buffer 0)
    __syncthreads();

#pragma unroll 1
    for (int tc = 0; tc < 16; ++tc) {
        // ---- stage x chunk -> Al (bf16), seq[b][t][i=c*64+w] = x[b][c][t][w]
#pragma unroll
        for (int it = 0; it < 6; ++it) {
            int flat = it*512 + tid;              // [0,3072) float4s
            int w4   = flat & 15;
            int tt   = (flat >> 4) & 3;
            int rest = flat >> 6;                 // b*3 + c
            int c = rest % 3;
            int b = rest / 3;
            const float4_t v = *(const float4_t*)(
                x + ((((bbase + b)*3 + c) << 6) + (tc*4 + tt))*64 + (w4 << 2));
            ushort4_t o;
            o.x = f2b(v.x); o.y = f2b(v.y); o.z = f2b(v.z); o.w = f2b(v.w);
            *(ushort4_t*)(Al + tt*3200 + b*200 + (c << 6) + (w4 << 2)) = o;
        }
        __syncthreads();

        // ---- input projections for 4 steps -> Pl
#pragma unroll
        for (int m = 0; m < 3; ++m)
#pragma unroll
            for (int n = 0; n < 2; ++n) {
                const int col = 32*wv + 16*n + l16;
                const ushort_t* bsrc = win + m*49152 + col*192 + l4*8;
                short8_t bk[6];
#pragma unroll
                for (int k = 0; k < 6; ++k) bk[k] = *(const short8_t*)(bsrc + k*32);
                const float bs = bias_mn[m][n];
                float4_t ac[4];
#pragma unroll
                for (int t = 0; t < 4; ++t) ac[t] = (float4_t){bs, bs, bs, bs};
#pragma unroll
                for (int k = 0; k < 6; ++k) {
#pragma unroll
                    for (int t = 0; t < 4; ++t) {
                        int off = t*3200 + l16*200 + k*32 + l4*8;
                        asm volatile("" : "+v"(off));   // defeat LICM/CSE across (m,n)
                        const short8_t a = *(const short8_t*)(Al + off);
                        ac[t] = __builtin_amdgcn_mfma_f32_16x16x32_bf16(a, bk[k], ac[t], 0, 0, 0);
                    }
                }
#pragma unroll
                for (int t = 0; t < 4; ++t) {
                    ushort4_t o;
                    o.x = f2b(ac[t].x); o.y = f2b(ac[t].y);
                    o.z = f2b(ac[t].z); o.w = f2b(ac[t].w);
                    *(ushort4_t*)(Pl + ((((t*8 + wv)*3 + m)*2 + n) << 8) + (lane << 2)) = o;
                }
            }
        __syncthreads();

        // ---- 4 recurrent steps
#pragma unroll 1
        for (int t = 0; t < 4; ++t) {
            const int step = tc*4 + t;
            const int cur = step & 1;
            const int nxt = cur ^ 1;

            float4_t acc[3][2];
#pragma unroll
            for (int m = 0; m < 3; ++m)
#pragma unroll
                for (int n = 0; n < 2; ++n) {
                    const ushort4_t p = *(const ushort4_t*)(
                        Pl + ((((t*8 + wv)*3 + m)*2 + n) << 8) + (lane << 2));
                    acc[m][n] = (float4_t){b2f(p.x), b2f(p.y), b2f(p.z), b2f(p.w)};
                }
#pragma unroll
            for (int k = 0; k < 8; ++k) {
                const short8_t a = *(const short8_t*)(Hb + cur*4224 + l16*264 + k*32 + l4*8);
#pragma unroll
                for (int m = 0; m < 3; ++m)
#pragma unroll
                    for (int n = 0; n < 2; ++n)
                        acc[m][n] = __builtin_amdgcn_mfma_f32_16x16x32_bf16(a, wr[m][n][k], acc[m][n], 0, 0, 0);
            }
            // epilogue: C element (row=l4*4+r [batch], col [hidden])
#pragma unroll
            for (int n = 0; n < 2; ++n) {
                const int col = 32*wv + 16*n + l16;
#pragma unroll
                for (int r = 0; r < 4; ++r) {
                    const float h   = hp[n][r];
                    const float cd  = tanhf_fast(acc[0][n][r]);
                    const float g   = sigf(acc[1][n][r]);
                    const float tau = 0.5f + 1.5f * sigf(acc[2][n][r]);
                    const float hn  = tanhf_fast(h + (g*cd - h) * frcp(tau));
                    hp[n][r] = hn;
                    Hb[nxt*4224 + (l4*4 + r)*264 + col] = f2b(hn);
                }
            }
            __syncthreads();
        }
    }

    // ---- head: out[b,o] = sum_j h[b,j]*head_w[o,j] + head_b[o]
    float* hf = (float*)(smem + 12800);      // [16][257] fp32, reuse Pl space
#pragma unroll
    for (int n = 0; n < 2; ++n) {
        const int col = 32*wv + 16*n + l16;
#pragma unroll
        for (int r = 0; r < 4; ++r)
            hf[(l4*4 + r)*257 + col] = hp[n][r];
    }
    __syncthreads();
    if (tid < 160) {
        const int r = tid / 10;
        const int o = tid - r*10;
        float s = head_b[o];
        const float* wrow = head_w + o*256;
        const float* hrow = hf + r*257;
#pragma unroll 8
        for (int j = 0; j < 256; ++j) s += hrow[j] * wrow[j];
        out[bbase*10 + tid] = s;
    }
}

extern "C" void kernel_launch(void* const* d_in, const int* in_sizes, int n_in,
                              void* d_out, int out_size, void* d_ws, size_t ws_size,
                              hipStream_t stream)
{
    const float* x     = (const float*)d_in[0];
    const float* ffi_w = (const float*)d_in[1];
    const float* ffi_b = (const float*)d_in[2];
    const float* ffr_w = (const float*)d_in[3];
    const float* ff_bs = (const float*)d_in[4];
    const float* gi_w  = (const float*)d_in[5];
    const float* gi_b  = (const float*)d_in[6];
    const float* gr_w  = (const float*)d_in[7];
    const float* g_bs  = (const float*)d_in[8];
    const float* ti_w  = (const float*)d_in[9];
    const float* ti_b  = (const float*)d_in[10];
    const float* tr_w  = (const float*)d_in[11];
    const float* t_bs  = (const float*)d_in[12];
    const float* hw    = (const float*)d_in[13];
    const float* hb    = (const float*)d_in[14];

    ushort_t* ws = (ushort_t*)d_ws;   // needs 688128 bytes

    cvt_w<<<1344, 256, 0, stream>>>(ffr_w, gr_w, tr_w, ffi_w, gi_w, ti_w, ws);
    ltc_fused<<<256, 512, 0, stream>>>(x, ws, ffi_b, ff_bs, gi_b, g_bs,
                                       ti_b, t_bs, hw, hb, (float*)d_out);
}

// Round 3
// 622.385 us; speedup vs baseline: 1.2909x; 1.2909x over previous
//
#include <hip/hip_runtime.h>

typedef unsigned short ushort_t;
typedef __attribute__((ext_vector_type(8))) short   short8_t;
typedef __attribute__((ext_vector_type(4))) float   float4_t;
typedef __attribute__((ext_vector_type(4))) unsigned short ushort4_t;

__device__ __forceinline__ ushort_t f2b(float f) {
    unsigned int u = __float_as_uint(f);
    u += 0x7FFFu + ((u >> 16) & 1u);      // round-to-nearest-even
    return (ushort_t)(u >> 16);
}
__device__ __forceinline__ float b2f(ushort_t s) {
    return __uint_as_float(((unsigned int)s) << 16);
}
__device__ __forceinline__ float frcp(float x) { return __builtin_amdgcn_rcpf(x); }
__device__ __forceinline__ float sigf(float x) { return frcp(1.f + __expf(-x)); }
__device__ __forceinline__ float tanhf_fast(float x) {
    return 1.f - 2.f * frcp(__expf(2.f * x) + 1.f);
}

// ---------------- weight convert: fp32 -> bf16 into ws ----------------
// ws layout (ushort elements): [0,196608): rec W [m][col 256][k 256]
//                              [196608, 344064): in W [m][col 256][k 192]
__global__ void cvt_w(const float* __restrict__ ffr, const float* __restrict__ gr,
                      const float* __restrict__ tr,  const float* __restrict__ ffi,
                      const float* __restrict__ gi,  const float* __restrict__ ti,
                      ushort_t* __restrict__ o)
{
    int i = blockIdx.x * 256 + threadIdx.x;   // exactly [0, 344064)
    float v;
    if (i < 196608) {
        int j = i & 65535;
        v = (i < 65536) ? ffr[j] : (i < 131072) ? gr[j] : tr[j];
    } else {
        int j = i - 196608;
        int jj = (j < 49152) ? j : (j < 98304) ? j - 49152 : j - 98304;
        v = (j < 49152) ? ffi[jj] : (j < 98304) ? gi[jj] : ti[jj];
    }
    o[i] = f2b(v);
}

// ---------------- fused LTC kernel ----------------
// 256 blocks x 512 thr (8 waves), 1 block/CU. Block owns 16 batch rows.
// Wave wv owns hidden cols [32wv, 32wv+32) (2 n-tiles) of all 3 matrices.
// Rec weights: m=0,1 full + m=2 k<128 resident in regs (160 VGPRs); m=2
// k>=128 streamed from L2 each step. Proj: n-split, full-t accumulators
// (pac[3][4]), B streamed per kf. Hb: 2 buffers x 4224 el ([16 rows][264]).
// One barrier per step; x-staging for chunk tc+1 folded into steps 0..2.
__global__ __launch_bounds__(512, 2) void ltc_fused(
    const float* __restrict__ x,
    const ushort_t* __restrict__ wbf,
    const float* __restrict__ ff_in_b, const float* __restrict__ ff_bias,
    const float* __restrict__ g_in_b,  const float* __restrict__ g_bias,
    const float* __restrict__ t_in_b,  const float* __restrict__ t_bias,
    const float* __restrict__ head_w,  const float* __restrict__ head_b,
    float* __restrict__ out)
{
    __shared__ __align__(16) ushort_t smem[70400];
    ushort_t* Al = smem;                 // 12800 el
    ushort_t* Pl = smem + 12800;         // 49152 el
    ushort_t* Hb = smem + 61952;         // 8448 el = 2 x 4224

    const int tid   = threadIdx.x;
    const int lane  = tid & 63;
    const int wv    = tid >> 6;
    const int l16   = lane & 15;
    const int l4    = lane >> 4;
    const int bbase = blockIdx.x << 4;

    const ushort_t* wrec = wbf;
    const ushort_t* win  = wbf + 196608;

    const int col0 = 32*wv + l16;        // n=0 col
    const int col1 = col0 + 16;          // n=1 col

    // resident rec-weight B-fragments (B[k][c] = Wrec[c][k])
    short8_t wr01[2][2][8];              // m=0,1 : 128 regs
    short8_t wr2[2][4];                  // m=2, kk 0..3 : 32 regs
#pragma unroll
    for (int m = 0; m < 2; ++m)
#pragma unroll
        for (int n = 0; n < 2; ++n) {
            const ushort_t* src = wrec + (m << 16) + ((n ? col1 : col0) << 8) + l4*8;
#pragma unroll
            for (int k = 0; k < 8; ++k)
                wr01[m][n][k] = *(const short8_t*)(src + k*32);
        }
#pragma unroll
    for (int n = 0; n < 2; ++n) {
        const ushort_t* src = wrec + (2 << 16) + ((n ? col1 : col0) << 8) + l4*8;
#pragma unroll
        for (int k = 0; k < 4; ++k)
            wr2[n][k] = *(const short8_t*)(src + k*32);
    }

    float hp[2][4];
#pragma unroll
    for (int n = 0; n < 2; ++n)
#pragma unroll
        for (int r = 0; r < 4; ++r) hp[n][r] = 0.f;

    for (int i = tid; i < 4224; i += 512) Hb[i] = 0;   // h0 = 0 (buffer 0)

    // stage chunk 0 into Al
#pragma unroll 1
    for (int p = 0; p < 6; ++p) {
        int flat = p*512 + tid;               // [0,3072) float4s
        int w4   = flat & 15;
        int tt   = (flat >> 4) & 3;
        int rest = flat >> 6;                 // b*3 + c
        int c = rest % 3;
        int b = rest / 3;
        const float4_t v = *(const float4_t*)(
            x + (((bbase + b)*3 + c)*4096) + tt*64 + (w4 << 2));
        ushort4_t o;
        o.x = f2b(v.x); o.y = f2b(v.y); o.z = f2b(v.z); o.w = f2b(v.w);
        *(ushort4_t*)(Al + tt*3200 + b*200 + (c << 6) + (w4 << 2)) = o;
    }
    __syncthreads();

#pragma unroll 1
    for (int tc = 0; tc < 16; ++tc) {
        // ======== input projection for this chunk (reads Al, writes own-lane Pl)
#pragma unroll 1
        for (int n = 0; n < 2; ++n) {
            const int col = n ? col1 : col0;
            float bs[3];
            bs[0] = ff_in_b[col] + ff_bias[col];
            bs[1] = g_in_b[col]  + g_bias[col];
            bs[2] = t_in_b[col]  + t_bias[col];
            float4_t pac[3][4];
#pragma unroll
            for (int m = 0; m < 3; ++m)
#pragma unroll
                for (int t = 0; t < 4; ++t)
                    pac[m][t] = (float4_t){bs[m], bs[m], bs[m], bs[m]};
            const ushort_t* wc = win + col*192 + l4*8;
#pragma unroll
            for (int kf = 0; kf < 6; ++kf) {
                const short8_t bk0 = *(const short8_t*)(wc +          kf*32);
                const short8_t bk1 = *(const short8_t*)(wc + 49152  + kf*32);
                const short8_t bk2 = *(const short8_t*)(wc + 98304  + kf*32);
#pragma unroll
                for (int t = 0; t < 4; ++t) {
                    const short8_t a = *(const short8_t*)(
                        Al + t*3200 + l16*200 + kf*32 + l4*8);
                    pac[0][t] = __builtin_amdgcn_mfma_f32_16x16x32_bf16(a, bk0, pac[0][t], 0, 0, 0);
                    pac[1][t] = __builtin_amdgcn_mfma_f32_16x16x32_bf16(a, bk1, pac[1][t], 0, 0, 0);
                    pac[2][t] = __builtin_amdgcn_mfma_f32_16x16x32_bf16(a, bk2, pac[2][t], 0, 0, 0);
                }
            }
#pragma unroll
            for (int m = 0; m < 3; ++m)
#pragma unroll
                for (int t = 0; t < 4; ++t) {
                    ushort4_t o;
                    o.x = f2b(pac[m][t].x); o.y = f2b(pac[m][t].y);
                    o.z = f2b(pac[m][t].z); o.w = f2b(pac[m][t].w);
                    *(ushort4_t*)(Pl + ((((t*8 + wv)*3 + m)*2 + n) << 8) + (lane << 2)) = o;
                }
        }

        // ======== 4 recurrent steps (1 barrier each); x-staging for chunk
        // tc+1 folded into steps 0..2 (2 float4 parts per step).
#pragma unroll 1
        for (int t = 0; t < 4; ++t) {
            const int step = tc*4 + t;
            const int cur = step & 1;
            const int nxt = cur ^ 1;

            __syncthreads();

            // -- issue staging loads early (hidden under MFMA)
            const bool do_stage = (t < 3) && (tc < 15);
            float4_t sv0, sv1;
            int sa0 = 0, sa1 = 0;
            if (do_stage) {
                const int tcn = tc + 1;
#pragma unroll
                for (int q = 0; q < 2; ++q) {
                    int flat = (t*2 + q)*512 + tid;
                    int w4   = flat & 15;
                    int tt   = (flat >> 4) & 3;
                    int rest = flat >> 6;
                    int c = rest % 3;
                    int b = rest / 3;
                    const float4_t v = *(const float4_t*)(
                        x + (((bbase + b)*3 + c)*4096) + (tcn*4 + tt)*64 + (w4 << 2));
                    int ai = tt*3200 + b*200 + (c << 6) + (w4 << 2);
                    if (q == 0) { sv0 = v; sa0 = ai; } else { sv1 = v; sa1 = ai; }
                }
            }

            // -- stream m=2 high-k rec fragments (consumed at kk>=4)
            const ushort_t* wt0 = wrec + (2 << 16) + (col0 << 8) + l4*8;
            const ushort_t* wt1 = wrec + (2 << 16) + (col1 << 8) + l4*8;
            short8_t s0[4], s1[4];
#pragma unroll
            for (int k = 0; k < 4; ++k) {
                s0[k] = *(const short8_t*)(wt0 + (k + 4)*32);
                s1[k] = *(const short8_t*)(wt1 + (k + 4)*32);
            }

            // -- init acc from Pl (own-lane, no barrier needed)
            float4_t acc[3][2];
#pragma unroll
            for (int m = 0; m < 3; ++m)
#pragma unroll
                for (int n = 0; n < 2; ++n) {
                    const ushort4_t p = *(const ushort4_t*)(
                        Pl + ((((t*8 + wv)*3 + m)*2 + n) << 8) + (lane << 2));
                    acc[m][n] = (float4_t){b2f(p.x), b2f(p.y), b2f(p.z), b2f(p.w)};
                }

            // -- K loop: A from Hb (shared), B resident/streamed
#pragma unroll
            for (int kk = 0; kk < 4; ++kk) {
                const short8_t a = *(const short8_t*)(
                    Hb + cur*4224 + l16*264 + kk*32 + l4*8);
                acc[0][0] = __builtin_amdgcn_mfma_f32_16x16x32_bf16(a, wr01[0][0][kk], acc[0][0], 0, 0, 0);
                acc[0][1] = __builtin_amdgcn_mfma_f32_16x16x32_bf16(a, wr01[0][1][kk], acc[0][1], 0, 0, 0);
                acc[1][0] = __builtin_amdgcn_mfma_f32_16x16x32_bf16(a, wr01[1][0][kk], acc[1][0], 0, 0, 0);
                acc[1][1] = __builtin_amdgcn_mfma_f32_16x16x32_bf16(a, wr01[1][1][kk], acc[1][1], 0, 0, 0);
                acc[2][0] = __builtin_amdgcn_mfma_f32_16x16x32_bf16(a, wr2[0][kk], acc[2][0], 0, 0, 0);
                acc[2][1] = __builtin_amdgcn_mfma_f32_16x16x32_bf16(a, wr2[1][kk], acc[2][1], 0, 0, 0);
            }
#pragma unroll
            for (int kk = 4; kk < 8; ++kk) {
                const short8_t a = *(const short8_t*)(
                    Hb + cur*4224 + l16*264 + kk*32 + l4*8);
                acc[0][0] = __builtin_amdgcn_mfma_f32_16x16x32_bf16(a, wr01[0][0][kk], acc[0][0], 0, 0, 0);
                acc[0][1] = __builtin_amdgcn_mfma_f32_16x16x32_bf16(a, wr01[0][1][kk], acc[0][1], 0, 0, 0);
                acc[1][0] = __builtin_amdgcn_mfma_f32_16x16x32_bf16(a, wr01[1][0][kk], acc[1][0], 0, 0, 0);
                acc[1][1] = __builtin_amdgcn_mfma_f32_16x16x32_bf16(a, wr01[1][1][kk], acc[1][1], 0, 0, 0);
                acc[2][0] = __builtin_amdgcn_mfma_f32_16x16x32_bf16(a, s0[kk-4], acc[2][0], 0, 0, 0);
                acc[2][1] = __builtin_amdgcn_mfma_f32_16x16x32_bf16(a, s1[kk-4], acc[2][1], 0, 0, 0);
            }

            // -- finish staging writes to Al
            if (do_stage) {
                ushort4_t o;
                o.x = f2b(sv0.x); o.y = f2b(sv0.y); o.z = f2b(sv0.z); o.w = f2b(sv0.w);
                *(ushort4_t*)(Al + sa0) = o;
                o.x = f2b(sv1.x); o.y = f2b(sv1.y); o.z = f2b(sv1.z); o.w = f2b(sv1.w);
                *(ushort4_t*)(Al + sa1) = o;
            }

            // -- epilogue: C element (row=l4*4+r [batch], col [hidden])
#pragma unroll
            for (int n = 0; n < 2; ++n) {
                const int col = n ? col1 : col0;
#pragma unroll
                for (int r = 0; r < 4; ++r) {
                    const float h   = hp[n][r];
                    const float cd  = tanhf_fast(acc[0][n][r]);
                    const float g   = sigf(acc[1][n][r]);
                    const float tau = 0.5f + 1.5f * sigf(acc[2][n][r]);
                    const float hn  = tanhf_fast(h + (g*cd - h) * frcp(tau));
                    hp[n][r] = hn;
                    Hb[nxt*4224 + (l4*4 + r)*264 + col] = f2b(hn);
                }
            }
        }
    }
    __syncthreads();

    // ---- head: out[b,o] = sum_j h[b,j]*head_w[o,j] + head_b[o]
    float* hf = (float*)(smem + 12800);      // [16][257] fp32, reuse Pl space
#pragma unroll
    for (int n = 0; n < 2; ++n) {
        const int col = n ? col1 : col0;
#pragma unroll
        for (int r = 0; r < 4; ++r)
            hf[(l4*4 + r)*257 + col] = hp[n][r];
    }
    __syncthreads();
    if (tid < 160) {
        const int r = tid / 10;
        const int o = tid - r*10;
        float s = head_b[o];
        const float* wrow = head_w + o*256;
        const float* hrow = hf + r*257;
#pragma unroll 8
        for (int j = 0; j < 256; ++j) s += hrow[j] * wrow[j];
        out[bbase*10 + tid] = s;
    }
}

extern "C" void kernel_launch(void* const* d_in, const int* in_sizes, int n_in,
                              void* d_out, int out_size, void* d_ws, size_t ws_size,
                              hipStream_t stream)
{
    const float* x     = (const float*)d_in[0];
    const float* ffi_w = (const float*)d_in[1];
    const float* ffi_b = (const float*)d_in[2];
    const float* ffr_w = (const float*)d_in[3];
    const float* ff_bs = (const float*)d_in[4];
    const float* gi_w  = (const float*)d_in[5];
    const float* gi_b  = (const float*)d_in[6];
    const float* gr_w  = (const float*)d_in[7];
    const float* g_bs  = (const float*)d_in[8];
    const float* ti_w  = (const float*)d_in[9];
    const float* ti_b  = (const float*)d_in[10];
    const float* tr_w  = (const float*)d_in[11];
    const float* t_bs  = (const float*)d_in[12];
    const float* hw    = (const float*)d_in[13];
    const float* hb    = (const float*)d_in[14];

    ushort_t* ws = (ushort_t*)d_ws;   // needs 688128 bytes

    cvt_w<<<1344, 256, 0, stream>>>(ffr_w, gr_w, tr_w, ffi_w, gi_w, ti_w, ws);
    ltc_fused<<<256, 512, 0, stream>>>(x, ws, ffi_b, ff_bs, gi_b, g_bs,
                                       ti_b, t_bs, hw, hb, (float*)d_out);
}

// Round 4
// 593.357 us; speedup vs baseline: 1.3540x; 1.0489x over previous
//
#include <hip/hip_runtime.h>

typedef unsigned short ushort_t;
typedef __attribute__((ext_vector_type(8))) short   short8_t;
typedef __attribute__((ext_vector_type(4))) float   float4_t;
typedef __attribute__((ext_vector_type(4))) unsigned short ushort4_t;

__device__ __forceinline__ ushort_t f2b(float f) {
    unsigned int u = __float_as_uint(f);
    u += 0x7FFFu + ((u >> 16) & 1u);      // round-to-nearest-even
    return (ushort_t)(u >> 16);
}
__device__ __forceinline__ float b2f(ushort_t s) {
    return __uint_as_float(((unsigned int)s) << 16);
}
__device__ __forceinline__ float frcp(float x) { return __builtin_amdgcn_rcpf(x); }
__device__ __forceinline__ float sigf(float x) { return frcp(1.f + __expf(-x)); }
__device__ __forceinline__ float tanhf_fast(float x) {
    return 1.f - 2.f * frcp(__expf(2.f * x) + 1.f);
}

// ---------------- weight convert: fp32 -> bf16 fragment-order ----------------
// Fragment order: for (m, tn=col-tile/16, kf) the 64 lanes' short8 B-fragments
// stored contiguously (lane*8 ushorts). Lane frag: col = tn*16 + (lane&15),
// k = kf*32 + (lane>>4)*8 + j. Hot-kernel loads become base + lane*16B.
// ws (ushort): [0,196608): rec frags ((m*16+tn)*8+kf)*512 + lane*8 + j
//              [196608, 344064): in frags ((m*16+tn)*6+kf)*512 + lane*8 + j
__global__ void cvt_w(const float* __restrict__ ffr, const float* __restrict__ gr,
                      const float* __restrict__ tr,  const float* __restrict__ ffi,
                      const float* __restrict__ gi,  const float* __restrict__ ti,
                      ushort_t* __restrict__ o)
{
    int i = blockIdx.x * 256 + threadIdx.x;   // exactly [0, 344064)
    float v;
    if (i < 196608) {
        int j    = i & 7;
        int lane = (i >> 3) & 63;
        int kf   = (i >> 9) & 7;
        int tn   = (i >> 12) & 15;
        int m    = i >> 16;
        int col  = tn*16 + (lane & 15);
        int k    = kf*32 + (lane >> 4)*8 + j;
        const float* W = (m == 0) ? ffr : (m == 1) ? gr : tr;
        v = W[(col << 8) + k];
    } else {
        int f    = i - 196608;
        int j    = f & 7;
        int lane = (f >> 3) & 63;
        int q    = f >> 9;            // [0,288) = (m*16+tn)*6+kf
        int kf   = q % 6;
        int tt   = q / 6;
        int tn   = tt & 15;
        int m    = tt >> 4;
        int col  = tn*16 + (lane & 15);
        int k    = kf*32 + (lane >> 4)*8 + j;
        const float* W = (m == 0) ? ffi : (m == 1) ? gi : ti;
        v = W[col*192 + k];
    }
    o[i] = f2b(v);
}

// ---------------- fused LTC kernel ----------------
// 256 blocks x 512 thr (8 waves), 1 block/CU. Block owns 16 batch rows.
// Wave wv owns hidden col-tiles tn0=2wv, tn1=2wv+1. Rec weights m=0,1 full +
// m=2 k<128 resident (160 VGPRs); m=2 k>=128 streamed (coalesced) per step.
// Proj: n-split, pac[3][4], B streamed per kf (coalesced fragment loads).
// Hb: 2 x 4224 el ([16 rows][264]). One barrier per step; x-staging for
// chunk tc+1 folded into steps 0..2.
__global__ __launch_bounds__(512, 2) void ltc_fused(
    const float* __restrict__ x,
    const ushort_t* __restrict__ wbf,
    const float* __restrict__ ff_in_b, const float* __restrict__ ff_bias,
    const float* __restrict__ g_in_b,  const float* __restrict__ g_bias,
    const float* __restrict__ t_in_b,  const float* __restrict__ t_bias,
    const float* __restrict__ head_w,  const float* __restrict__ head_b,
    float* __restrict__ out)
{
    __shared__ __align__(16) ushort_t smem[70400];
    ushort_t* Al = smem;                 // 12800 el
    ushort_t* Pl = smem + 12800;         // 49152 el
    ushort_t* Hb = smem + 61952;         // 8448 el = 2 x 4224

    const int tid   = threadIdx.x;
    const int lane  = tid & 63;
    const int wv    = tid >> 6;
    const int l16   = lane & 15;
    const int l4    = lane >> 4;
    const int bbase = blockIdx.x << 4;

    const ushort_t* recF = wbf;
    const ushort_t* inF  = wbf + 196608;

    const int tn0  = 2*wv;
    const int tn1  = 2*wv + 1;
    const int col0 = 32*wv + l16;        // n=0 col (for bias/epilogue)
    const int col1 = col0 + 16;          // n=1 col

    // resident rec-weight B-fragments, coalesced loads (base + lane*16B)
    short8_t wr01[2][2][8];              // m=0,1 : 128 regs
    short8_t wr2[2][4];                  // m=2, kf 0..3 : 32 regs
#pragma unroll
    for (int m = 0; m < 2; ++m)
#pragma unroll
        for (int n = 0; n < 2; ++n) {
            const int tn = n ? tn1 : tn0;
#pragma unroll
            for (int k = 0; k < 8; ++k)
                wr01[m][n][k] = *(const short8_t*)(
                    recF + (((m*16 + tn)*8 + k) << 9) + lane*8);
        }
#pragma unroll
    for (int n = 0; n < 2; ++n) {
        const int tn = n ? tn1 : tn0;
#pragma unroll
        for (int k = 0; k < 4; ++k)
            wr2[n][k] = *(const short8_t*)(
                recF + (((32 + tn)*8 + k) << 9) + lane*8);
    }

    float hp[2][4];
#pragma unroll
    for (int n = 0; n < 2; ++n)
#pragma unroll
        for (int r = 0; r < 4; ++r) hp[n][r] = 0.f;

    for (int i = tid; i < 4224; i += 512) Hb[i] = 0;   // h0 = 0 (buffer 0)

    // stage chunk 0 into Al
#pragma unroll 1
    for (int p = 0; p < 6; ++p) {
        int flat = p*512 + tid;               // [0,3072) float4s
        int w4   = flat & 15;
        int tt   = (flat >> 4) & 3;
        int rest = flat >> 6;                 // b*3 + c
        int c = rest % 3;
        int b = rest / 3;
        const float4_t v = *(const float4_t*)(
            x + (((bbase + b)*3 + c)*4096) + tt*64 + (w4 << 2));
        ushort4_t o;
        o.x = f2b(v.x); o.y = f2b(v.y); o.z = f2b(v.z); o.w = f2b(v.w);
        *(ushort4_t*)(Al + tt*3200 + b*200 + (c << 6) + (w4 << 2)) = o;
    }
    __syncthreads();

#pragma unroll 1
    for (int tc = 0; tc < 16; ++tc) {
        // ======== input projection (reads Al; coalesced B frags; own-lane Pl)
#pragma unroll 1
        for (int n = 0; n < 2; ++n) {
            const int tn  = n ? tn1 : tn0;
            const int col = n ? col1 : col0;
            float bs[3];
            bs[0] = ff_in_b[col] + ff_bias[col];
            bs[1] = g_in_b[col]  + g_bias[col];
            bs[2] = t_in_b[col]  + t_bias[col];
            float4_t pac[3][4];
#pragma unroll
            for (int m = 0; m < 3; ++m)
#pragma unroll
                for (int t = 0; t < 4; ++t)
                    pac[m][t] = (float4_t){bs[m], bs[m], bs[m], bs[m]};
            const ushort_t* wcb = inF + lane*8;
#pragma unroll
            for (int kf = 0; kf < 6; ++kf) {
                const short8_t bk0 = *(const short8_t*)(wcb + (((     tn)*6 + kf) << 9));
                const short8_t bk1 = *(const short8_t*)(wcb + (((16 + tn)*6 + kf) << 9));
                const short8_t bk2 = *(const short8_t*)(wcb + (((32 + tn)*6 + kf) << 9));
#pragma unroll
                for (int t = 0; t < 4; ++t) {
                    const short8_t a = *(const short8_t*)(
                        Al + t*3200 + l16*200 + kf*32 + l4*8);
                    pac[0][t] = __builtin_amdgcn_mfma_f32_16x16x32_bf16(a, bk0, pac[0][t], 0, 0, 0);
                    pac[1][t] = __builtin_amdgcn_mfma_f32_16x16x32_bf16(a, bk1, pac[1][t], 0, 0, 0);
                    pac[2][t] = __builtin_amdgcn_mfma_f32_16x16x32_bf16(a, bk2, pac[2][t], 0, 0, 0);
                }
            }
#pragma unroll
            for (int m = 0; m < 3; ++m)
#pragma unroll
                for (int t = 0; t < 4; ++t) {
                    ushort4_t o;
                    o.x = f2b(pac[m][t].x); o.y = f2b(pac[m][t].y);
                    o.z = f2b(pac[m][t].z); o.w = f2b(pac[m][t].w);
                    *(ushort4_t*)(Pl + ((((t*8 + wv)*3 + m)*2 + n) << 8) + (lane << 2)) = o;
                }
        }

        // ======== 4 recurrent steps (1 barrier each)
#pragma unroll 1
        for (int t = 0; t < 4; ++t) {
            const int step = tc*4 + t;
            const int cur = step & 1;
            const int nxt = cur ^ 1;

            __syncthreads();

            // -- issue staging loads early (hidden under MFMA)
            const bool do_stage = (t < 3) && (tc < 15);
            float4_t sv0, sv1;
            int sa0 = 0, sa1 = 0;
            if (do_stage) {
                const int tcn = tc + 1;
#pragma unroll
                for (int q = 0; q < 2; ++q) {
                    int flat = (t*2 + q)*512 + tid;
                    int w4   = flat & 15;
                    int tt   = (flat >> 4) & 3;
                    int rest = flat >> 6;
                    int c = rest % 3;
                    int b = rest / 3;
                    const float4_t v = *(const float4_t*)(
                        x + (((bbase + b)*3 + c)*4096) + (tcn*4 + tt)*64 + (w4 << 2));
                    int ai = tt*3200 + b*200 + (c << 6) + (w4 << 2);
                    if (q == 0) { sv0 = v; sa0 = ai; } else { sv1 = v; sa1 = ai; }
                }
            }

            // -- stream m=2 high-k rec fragments (coalesced; consumed at kk>=4)
            short8_t s0[4], s1[4];
#pragma unroll
            for (int k = 0; k < 4; ++k) {
                s0[k] = *(const short8_t*)(recF + (((32 + tn0)*8 + k + 4) << 9) + lane*8);
                s1[k] = *(const short8_t*)(recF + (((32 + tn1)*8 + k + 4) << 9) + lane*8);
            }

            // -- init acc from Pl (own-lane, no barrier needed)
            float4_t acc[3][2];
#pragma unroll
            for (int m = 0; m < 3; ++m)
#pragma unroll
                for (int n = 0; n < 2; ++n) {
                    const ushort4_t p = *(const ushort4_t*)(
                        Pl + ((((t*8 + wv)*3 + m)*2 + n) << 8) + (lane << 2));
                    acc[m][n] = (float4_t){b2f(p.x), b2f(p.y), b2f(p.z), b2f(p.w)};
                }

            // -- K loop: A from Hb (shared), B resident/streamed
#pragma unroll
            for (int kk = 0; kk < 4; ++kk) {
                const short8_t a = *(const short8_t*)(
                    Hb + cur*4224 + l16*264 + kk*32 + l4*8);
                acc[0][0] = __builtin_amdgcn_mfma_f32_16x16x32_bf16(a, wr01[0][0][kk], acc[0][0], 0, 0, 0);
                acc[0][1] = __builtin_amdgcn_mfma_f32_16x16x32_bf16(a, wr01[0][1][kk], acc[0][1], 0, 0, 0);
                acc[1][0] = __builtin_amdgcn_mfma_f32_16x16x32_bf16(a, wr01[1][0][kk], acc[1][0], 0, 0, 0);
                acc[1][1] = __builtin_amdgcn_mfma_f32_16x16x32_bf16(a, wr01[1][1][kk], acc[1][1], 0, 0, 0);
                acc[2][0] = __builtin_amdgcn_mfma_f32_16x16x32_bf16(a, wr2[0][kk], acc[2][0], 0, 0, 0);
                acc[2][1] = __builtin_amdgcn_mfma_f32_16x16x32_bf16(a, wr2[1][kk], acc[2][1], 0, 0, 0);
            }
#pragma unroll
            for (int kk = 4; kk < 8; ++kk) {
                const short8_t a = *(const short8_t*)(
                    Hb + cur*4224 + l16*264 + kk*32 + l4*8);
                acc[0][0] = __builtin_amdgcn_mfma_f32_16x16x32_bf16(a, wr01[0][0][kk], acc[0][0], 0, 0, 0);
                acc[0][1] = __builtin_amdgcn_mfma_f32_16x16x32_bf16(a, wr01[0][1][kk], acc[0][1], 0, 0, 0);
                acc[1][0] = __builtin_amdgcn_mfma_f32_16x16x32_bf16(a, wr01[1][0][kk], acc[1][0], 0, 0, 0);
                acc[1][1] = __builtin_amdgcn_mfma_f32_16x16x32_bf16(a, wr01[1][1][kk], acc[1][1], 0, 0, 0);
                acc[2][0] = __builtin_amdgcn_mfma_f32_16x16x32_bf16(a, s0[kk-4], acc[2][0], 0, 0, 0);
                acc[2][1] = __builtin_amdgcn_mfma_f32_16x16x32_bf16(a, s1[kk-4], acc[2][1], 0, 0, 0);
            }

            // -- finish staging writes to Al
            if (do_stage) {
                ushort4_t o;
                o.x = f2b(sv0.x); o.y = f2b(sv0.y); o.z = f2b(sv0.z); o.w = f2b(sv0.w);
                *(ushort4_t*)(Al + sa0) = o;
                o.x = f2b(sv1.x); o.y = f2b(sv1.y); o.z = f2b(sv1.z); o.w = f2b(sv1.w);
                *(ushort4_t*)(Al + sa1) = o;
            }

            // -- epilogue: C element (row=l4*4+r [batch], col [hidden])
#pragma unroll
            for (int n = 0; n < 2; ++n) {
                const int col = n ? col1 : col0;
#pragma unroll
                for (int r = 0; r < 4; ++r) {
                    const float h   = hp[n][r];
                    const float cd  = tanhf_fast(acc[0][n][r]);
                    const float g   = sigf(acc[1][n][r]);
                    const float tau = 0.5f + 1.5f * sigf(acc[2][n][r]);
                    const float hn  = tanhf_fast(h + (g*cd - h) * frcp(tau));
                    hp[n][r] = hn;
                    Hb[nxt*4224 + (l4*4 + r)*264 + col] = f2b(hn);
                }
            }
        }
    }
    __syncthreads();

    // ---- head: out[b,o] = sum_j h[b,j]*head_w[o,j] + head_b[o]
    float* hf = (float*)(smem + 12800);      // [16][257] fp32, reuse Pl space
#pragma unroll
    for (int n = 0; n < 2; ++n) {
        const int col = n ? col1 : col0;
#pragma unroll
        for (int r = 0; r < 4; ++r)
            hf[(l4*4 + r)*257 + col] = hp[n][r];
    }
    __syncthreads();
    if (tid < 160) {
        const int r = tid / 10;
        const int o = tid - r*10;
        float s = head_b[o];
        const float* wrow = head_w + o*256;
        const float* hrow = hf + r*257;
#pragma unroll 8
        for (int j = 0; j < 256; ++j) s += hrow[j] * wrow[j];
        out[bbase*10 + tid] = s;
    }
}

extern "C" void kernel_launch(void* const* d_in, const int* in_sizes, int n_in,
                              void* d_out, int out_size, void* d_ws, size_t ws_size,
                              hipStream_t stream)
{
    const float* x     = (const float*)d_in[0];
    const float* ffi_w = (const float*)d_in[1];
    const float* ffi_b = (const float*)d_in[2];
    const float* ffr_w = (const float*)d_in[3];
    const float* ff_bs = (const float*)d_in[4];
    const float* gi_w  = (const float*)d_in[5];
    const float* gi_b  = (const float*)d_in[6];
    const float* gr_w  = (const float*)d_in[7];
    const float* g_bs  = (const float*)d_in[8];
    const float* ti_w  = (const float*)d_in[9];
    const float* ti_b  = (const float*)d_in[10];
    const float* tr_w  = (const float*)d_in[11];
    const float* t_bs  = (const float*)d_in[12];
    const float* hw    = (const float*)d_in[13];
    const float* hb    = (const float*)d_in[14];

    ushort_t* ws = (ushort_t*)d_ws;   // needs 688128 bytes

    cvt_w<<<1344, 256, 0, stream>>>(ffr_w, gr_w, tr_w, ffi_w, gi_w, ti_w, ws);
    ltc_fused<<<256, 512, 0, stream>>>(x, ws, ffi_b, ff_bs, gi_b, g_bs,
                                       ti_b, t_bs, hw, hb, (float*)d_out);
}